// Round 1
// baseline (212.880 us; speedup 1.0000x reference)
//
#include <hip/hip_runtime.h>
#include <math.h>

#define N_FFT   4096
#define IR_LEN  2000
#define PFRAME  80
#define NFRAMES 300
#define NBATCH  2
#define T_TOTAL (NFRAMES * PFRAME)   // 24000
#define NCOEF   25

// ---------------------------------------------------------------------------
// Kernel A: per (batch,frame) row, compute min-phase IR:
//   C[f] = sum_k c[k] e^{-2pi i f k / 4096}   (25-tap direct DFT, rotation recurrence)
//   E[f] = exp(C[f])                          (half-spectrum, conj symmetry for rest)
//   h[n] = Re( (1/4096) sum_f E[f] e^{+2pi i f n/4096} ), n < 2000
// IFFT factored 4096 = 64 x 64:
//   f = 64a + b, n = 64c + d
//   G[d][b]  = sum_a E[64a+b] * e^{+2pi i a d/64}
//   G'[d][b] = G[d][b] * e^{+2pi i b d/4096}
//   h[64c+d] = (1/4096) sum_b G'[d][b] * e^{+2pi i b c/64}   (real part)
// ---------------------------------------------------------------------------
__global__ __launch_bounds__(256) void minphase_ir_kernel(
        const float* __restrict__ mc, float* __restrict__ h_out) {
    __shared__ float EHr[2052], EHi[2052];     // half spectrum f=0..2048 (SoA)
    __shared__ float Gr[64 * 65], Gi[64 * 65]; // stride 65: lane-d-major reads 2-way only
    __shared__ float twr64[64], twi64[64];     // e^{+2pi i j/64}
    __shared__ float csh[NCOEF];

    const int row = blockIdx.x;       // 0..599  (batch*300 + frame)
    const int tid = threadIdx.x;

    if (tid < NCOEF) csh[tid] = mc[row * NCOEF + tid];
    if (tid < 64) {
        float a = (2.0f * (float)M_PI / 64.0f) * (float)tid;
        float s, c; sincosf(a, &s, &c);
        twr64[tid] = c; twi64[tid] = s;
    }
    __syncthreads();

    // --- E[f] = exp(C[f]), f = 0..2048 ---
    for (int f = tid; f <= 2048; f += 256) {
        float ang = -(2.0f * (float)M_PI / 4096.0f) * (float)f;
        float ws, wc; sincosf(ang, &ws, &wc);   // per-k rotation e^{-2pi i f/4096}
        float cr = 1.0f, ci = 0.0f;
        float Cr = 0.0f, Ci = 0.0f;
        #pragma unroll
        for (int k = 0; k < NCOEF; k++) {
            float cc = csh[k];
            Cr += cc * cr; Ci += cc * ci;
            float nr = cr * wc - ci * ws;
            float ni = cr * ws + ci * wc;
            cr = nr; ci = ni;
        }
        float m = expf(Cr);
        float si, co; sincosf(Ci, &si, &co);
        EHr[f] = m * co; EHi[f] = m * si;
    }
    __syncthreads();

    // --- Stage 1: G'[d][b] ---
    {
        const int d  = tid >> 2;          // 0..63
        const int b0 = (tid & 3) * 16;    // 16 consecutive b per thread
        float accr[16], acci[16];
        #pragma unroll
        for (int i = 0; i < 16; i++) { accr[i] = 0.0f; acci[i] = 0.0f; }
        for (int a = 0; a < 64; a++) {
            const int ti = (a * d) & 63;
            const float tr = twr64[ti], tii = twi64[ti];
            const int base = a * 64 + b0;
            #pragma unroll
            for (int i = 0; i < 16; i++) {
                const int idx = base + i;
                float er, ei;
                if (idx <= 2048) { er = EHr[idx];        ei =  EHi[idx]; }
                else             { er = EHr[4096 - idx]; ei = -EHi[4096 - idx]; }
                accr[i] += er * tr - ei * tii;
                acci[i] += er * tii + ei * tr;
            }
        }
        #pragma unroll
        for (int i = 0; i < 16; i++) {
            const int b = b0 + i;
            float ang = (2.0f * (float)M_PI / 4096.0f) * (float)(b * d);
            float s, c; sincosf(ang, &s, &c);
            Gr[d * 65 + b] = accr[i] * c - acci[i] * s;
            Gi[d * 65 + b] = accr[i] * s + acci[i] * c;
        }
    }
    __syncthreads();

    // --- Stage 2: h[n] = (1/4096) Re( sum_b G'[d][b] tw64[b*c] ), n = 64c+d ---
    for (int n = tid; n < IR_LEN; n += 256) {
        const int cg = n >> 6, d = n & 63;
        float acc = 0.0f;
        for (int b = 0; b < 64; b++) {
            const int ti = (b * cg) & 63;
            acc += Gr[d * 65 + b] * twr64[ti] - Gi[d * 65 + b] * twi64[ti];
        }
        h_out[row * IR_LEN + n] = acc * (1.0f / 4096.0f);
    }
}

// ---------------------------------------------------------------------------
// Kernel B: time-varying FIR with on-the-fly frame interpolation.
//   y[b,t] = (1-w) * <h[n], xwin(t)> + w * <h[min(n+1,299)], xwin(t)>
// One block per (batch, frame); lanes 0..79 each produce one output sample.
// ---------------------------------------------------------------------------
__global__ __launch_bounds__(128) void fir_kernel(
        const float* __restrict__ x, const float* __restrict__ h,
        float* __restrict__ y) {
    __shared__ float h0[IR_LEN], h1[IR_LEN];
    __shared__ float xw[IR_LEN + PFRAME];   // 2080 (index 0..2078 used)

    const int row   = blockIdx.x;           // 0..599
    const int batch = row / NFRAMES;
    const int frame = row % NFRAMES;
    const int nn    = (frame + 1 < NFRAMES) ? frame + 1 : NFRAMES - 1;
    const int t0    = frame * PFRAME;
    const int tid   = threadIdx.x;

    const float* hp0 = h + (size_t)row * IR_LEN;
    const float* hp1 = h + (size_t)(batch * NFRAMES + nn) * IR_LEN;
    for (int i = tid; i < IR_LEN; i += 128) { h0[i] = hp0[i]; h1[i] = hp1[i]; }

    const int xbase = t0 - (IR_LEN - 1);
    for (int j = tid; j < IR_LEN + PFRAME; j += 128) {
        const int xi = xbase + j;
        xw[j] = (xi >= 0 && xi < T_TOTAL) ? x[batch * T_TOTAL + xi] : 0.0f;
    }
    __syncthreads();

    if (tid < PFRAME) {
        const float w = (float)tid * (1.0f / (float)PFRAME);
        const int off = (IR_LEN - 1) + tid;
        float s0 = 0.0f, s1 = 0.0f;
        for (int k = 0; k < IR_LEN; k++) {
            const float xv = xw[off - k];
            s0 += h0[k] * xv;
            s1 += h1[k] * xv;
        }
        y[batch * T_TOTAL + t0 + tid] = (1.0f - w) * s0 + w * s1;
    }
}

extern "C" void kernel_launch(void* const* d_in, const int* in_sizes, int n_in,
                              void* d_out, int out_size, void* d_ws, size_t ws_size,
                              hipStream_t stream) {
    const float* x  = (const float*)d_in[0];   // (2, 24000)
    const float* mc = (const float*)d_in[1];   // (2, 300, 25)
    float* y    = (float*)d_out;               // (2, 24000)
    float* h_ws = (float*)d_ws;                // 600 * 2000 floats = 4.8 MB

    minphase_ir_kernel<<<NBATCH * NFRAMES, 256, 0, stream>>>(mc, h_ws);
    fir_kernel<<<NBATCH * NFRAMES, 128, 0, stream>>>(x, h_ws, y);
}